// Round 5
// baseline (573.634 us; speedup 1.0000x reference)
//
#include <hip/hip_runtime.h>
#include <hip/hip_bf16.h>
#include <math.h>

#define NEG_SLOPE 0.2f

__device__ __forceinline__ void fma4(float4& a, const float4 w, const float s){
    a.x += w.x * s; a.y += w.y * s; a.z += w.z * s; a.w += w.w * s;
}

// ---------------- CSR build ----------------

__global__ void edge_count(const int* __restrict__ src, const int* __restrict__ dst,
                           int E, int* __restrict__ counts){
    int e = blockIdx.x * blockDim.x + threadIdx.x;
    if (e >= E) return;
    int s = src[e], d = dst[e];
    if (s != d) atomicAdd(&counts[d], 1);
}

__global__ void scan_block(const int* __restrict__ counts, int* __restrict__ offsets,
                           int* __restrict__ blockSums, int N){
    __shared__ int sh[256];
    int t = threadIdx.x;
    int i = blockIdx.x * 256 + t;
    int v = (i < N) ? counts[i] : 0;
    sh[t] = v; __syncthreads();
    for (int off = 1; off < 256; off <<= 1){
        int x = (t >= off) ? sh[t - off] : 0;
        __syncthreads();
        sh[t] += x;
        __syncthreads();
    }
    if (i < N) offsets[i] = sh[t] - v;           // exclusive
    if (t == 255) blockSums[blockIdx.x] = sh[255];
}

__global__ void scan_sums(int* __restrict__ blockSums, int nb){
    __shared__ int sh[256];
    int t = threadIdx.x;
    int v = (t < nb) ? blockSums[t] : 0;
    sh[t] = v; __syncthreads();
    for (int off = 1; off < 256; off <<= 1){
        int x = (t >= off) ? sh[t - off] : 0;
        __syncthreads();
        sh[t] += x;
        __syncthreads();
    }
    if (t < nb) blockSums[t] = sh[t] - v;        // exclusive
}

__global__ void scan_add(int* __restrict__ offsets, const int* __restrict__ blockSums, int N){
    int i = blockIdx.x * 256 + threadIdx.x;
    if (i < N) offsets[i] += blockSums[blockIdx.x];
}

__global__ void copy_int(const int* __restrict__ a, int* __restrict__ b, int N){
    int i = blockIdx.x * blockDim.x + threadIdx.x;
    if (i < N) b[i] = a[i];
}

__global__ void edge_scatter(const int* __restrict__ src, const int* __restrict__ dst,
                             int E, int* __restrict__ cursor, int* __restrict__ edge_src){
    int e = blockIdx.x * blockDim.x + threadIdx.x;
    if (e >= E) return;
    int s = src[e], d = dst[e];
    if (s != d){
        int pos = atomicAdd(&cursor[d], 1);
        edge_src[pos] = s;
    }
}

// ---------------- dual linear (64-row tiles, 4x16 register blocking) ----------------
// [xl | xr] = in @ [Wl | Wr] + [bl | br].
// Block: 64 rows x HC2 cols, NT = HC2 threads. Thread: 4 cols x 16 rows (64 accs).
// x-tile transposed in LDS, stride 68 floats (16B-aligned float4 reads,
// wave-uniform broadcast). Staging: 4 threads/row -> 64B-coalesced global reads,
// 2-way (free) LDS bank groups on transposed writes.
template<int K, int HC2, int NT>
__global__ __launch_bounds__(NT)
void dual_linear_t(const float* __restrict__ in,
                   const float* __restrict__ Wl, const float* __restrict__ bl,
                   const float* __restrict__ Wr, const float* __restrict__ br,
                   float* __restrict__ xl, float* __restrict__ xr, int N){
    constexpr int HC = HC2 / 2;
    constexpr int CG = HC2 / 4;        // col groups of 4
    constexpr int STR = 68;            // LDS stride (floats); 272B, 16B-aligned
    __shared__ __align__(16) float xsT[K * STR];
    const int tid = threadIdx.x;
    const int row0 = blockIdx.x * 64;

    // staging: thread -> (row r = tid>>2, k-phase q = tid&3)
    {
        const int r = tid >> 2, q = tid & 3;
        if (r < 64){
            int gr = row0 + r; if (gr > N - 1) gr = N - 1;
            const float* ip = in + (size_t)gr * K;
            #pragma unroll
            for (int ko = 0; ko < K; ko += 16){
                int k = ko + q * 4;
                float4 v = *(const float4*)&ip[k];
                xsT[(k + 0) * STR + r] = v.x;
                xsT[(k + 1) * STR + r] = v.y;
                xsT[(k + 2) * STR + r] = v.z;
                xsT[(k + 3) * STR + r] = v.w;
            }
        }
    }
    __syncthreads();

    const int cg = tid % CG, rg = tid / CG;
    const int c4 = cg * 4, r16 = rg * 16;
    const bool left = c4 < HC;
    const float* Wb = left ? (Wl + c4) : (Wr + (c4 - HC));
    const float* bb = left ? (bl + c4) : (br + (c4 - HC));
    const float4 bv = *(const float4*)bb;
    float4 acc[16];
    #pragma unroll
    for (int r = 0; r < 16; ++r) acc[r] = bv;

    const float* wp = Wb;
    const float* xp = &xsT[r16];
    #pragma unroll 2
    for (int k = 0; k < K; ++k){
        float4 wv = *(const float4*)wp;  wp += HC;
        float4 xa = *(const float4*)(xp + 0);
        float4 xb = *(const float4*)(xp + 4);
        float4 xc = *(const float4*)(xp + 8);
        float4 xd = *(const float4*)(xp + 12);
        xp += STR;
        fma4(acc[ 0], wv, xa.x); fma4(acc[ 1], wv, xa.y);
        fma4(acc[ 2], wv, xa.z); fma4(acc[ 3], wv, xa.w);
        fma4(acc[ 4], wv, xb.x); fma4(acc[ 5], wv, xb.y);
        fma4(acc[ 6], wv, xb.z); fma4(acc[ 7], wv, xb.w);
        fma4(acc[ 8], wv, xc.x); fma4(acc[ 9], wv, xc.y);
        fma4(acc[10], wv, xc.z); fma4(acc[11], wv, xc.w);
        fma4(acc[12], wv, xd.x); fma4(acc[13], wv, xd.y);
        fma4(acc[14], wv, xd.z); fma4(acc[15], wv, xd.w);
    }

    float* ob = left ? (xl + c4) : (xr + (c4 - HC));
    #pragma unroll
    for (int r = 0; r < 16; ++r){
        int row = row0 + r16 + r;
        if (row < N) *(float4*)&ob[(size_t)row * HC] = acc[r];
    }
}

// ---------------- GATv2 aggregation ----------------
// One wave per (node [, head]); 4 groups x 16 lanes, each an independent
// online softmax over a strided quarter of {self} U edges. Defer-max (THR=8):
// rescale only on record jumps; merge is exact for any per-group reference m.
// 2-deep pipeline: next edge's row load issued before current edge's math.
template<int H, bool MEAN>
__global__ __launch_bounds__(256)
void gatv2_agg(const float* __restrict__ xl, const float* __restrict__ xr,
               const float* __restrict__ att, const float* __restrict__ bias,
               const int* __restrict__ offsets, const int* __restrict__ counts,
               const int* __restrict__ edge_src,
               float* __restrict__ hout, int N){
    const int HC = H * 64;
    int wid  = (blockIdx.x * 256 + threadIdx.x) >> 6;
    int lane = threadIdx.x & 63;
    int g = lane >> 4, sl = lane & 15, cb = sl * 4;
    int n, h0, h1;
    if (MEAN){ n = wid; h0 = 0; h1 = H; }
    else     { n = wid / H; h0 = wid - n * H; h1 = h0 + 1; }
    if (n >= N) return;
    const int rs = offsets[n];
    const int total = counts[n] + 1;     // + implicit self loop (virtual idx 0)

    float ox = 0.f, oy = 0.f, oz = 0.f, ow = 0.f;
    for (int h = h0; h < h1; ++h){
        const float4 a4 = *(const float4*)&att[h * 64 + cb];
        const float4 q4 = *(const float4*)&xr[(size_t)n * HC + h * 64 + cb];
        const float* XT = xl + h * 64 + cb;
        float m = -INFINITY, den = 0.f;
        float ax = 0.f, ay = 0.f, az = 0.f, aw = 0.f;
        int j = g;
        if (j < total){
            int scur = (j == 0) ? n : edge_src[rs + j - 1];
            float4 xv = *(const float4*)&XT[(size_t)scur * HC];
            while (j < total){
                int jn = j + 4;
                int sn = (jn < total) ? edge_src[rs + jn - 1] : scur;  // jn>=4: never self
                float4 xvn = *(const float4*)&XT[(size_t)sn * HC];     // prefetch
                float t0 = q4.x + xv.x, t1 = q4.y + xv.y;
                float t2 = q4.z + xv.z, t3 = q4.w + xv.w;
                t0 = t0 > 0.f ? t0 : NEG_SLOPE * t0;
                t1 = t1 > 0.f ? t1 : NEG_SLOPE * t1;
                t2 = t2 > 0.f ? t2 : NEG_SLOPE * t2;
                t3 = t3 > 0.f ? t3 : NEG_SLOPE * t3;
                float p = a4.x * t0 + a4.y * t1 + a4.z * t2 + a4.w * t3;
                p += __shfl_xor(p, 1, 64);
                p += __shfl_xor(p, 2, 64);
                p += __shfl_xor(p, 4, 64);
                p += __shfl_xor(p, 8, 64);
                float d = p - m;                 // first iter: +inf
                if (d > 8.f){                    // rare: record jump -> rescale
                    float s = __expf(-d);        // first iter: exp(-inf)=0
                    den *= s; ax *= s; ay *= s; az *= s; aw *= s;
                    m = p; d = 0.f;
                }
                float eb = __expf(d);            // <= e^8, bounded
                den += eb;
                ax += eb * xv.x; ay += eb * xv.y;
                az += eb * xv.z; aw += eb * xv.w;
                xv = xvn; j = jn;
            }
        }
        // merge the 4 group states (exact for any reference m)
        #pragma unroll
        for (int off = 16; off <= 32; off <<= 1){
            float mo  = __shfl_xor(m,  off, 64);
            float dno = __shfl_xor(den, off, 64);
            float bx = __shfl_xor(ax, off, 64), by = __shfl_xor(ay, off, 64);
            float bz = __shfl_xor(az, off, 64), bw = __shfl_xor(aw, off, 64);
            float Mn = fmaxf(m, mo);
            float sa = (m  == -INFINITY) ? 0.f : __expf(m  - Mn);
            float sb = (mo == -INFINITY) ? 0.f : __expf(mo - Mn);
            den = den * sa + dno * sb;
            ax = ax * sa + bx * sb; ay = ay * sa + by * sb;
            az = az * sa + bz * sb; aw = aw * sa + bw * sb;
            m = Mn;
        }
        float inv = 1.f / den;                   // self loop: den > 0
        ox += ax * inv; oy += ay * inv; oz += az * inv; ow += aw * inv;
    }
    if (lane < 16){
        float4 o;
        if (MEAN){
            const float s = 1.f / H;
            const float4 bv = *(const float4*)&bias[cb];
            o.x = fmaxf(ox * s + bv.x, 0.f);
            o.y = fmaxf(oy * s + bv.y, 0.f);
            o.z = fmaxf(oz * s + bv.z, 0.f);
            o.w = fmaxf(ow * s + bv.w, 0.f);
            *(float4*)&hout[(size_t)n * 64 + cb] = o;
        } else {
            const float4 bv = *(const float4*)&bias[h0 * 64 + cb];
            o.x = fmaxf(ox + bv.x, 0.f);
            o.y = fmaxf(oy + bv.y, 0.f);
            o.z = fmaxf(oz + bv.z, 0.f);
            o.w = fmaxf(ow + bv.w, 0.f);
            *(float4*)&hout[(size_t)n * HC + h0 * 64 + cb] = o;
        }
    }
}

// ---------------- pooling (run-length local reduce; batch is sorted) ----------------
__global__ __launch_bounds__(256)
void pool_kernel(const float* __restrict__ h, const int* __restrict__ batch,
                 int N, float* __restrict__ gmx, float* __restrict__ gsum,
                 int* __restrict__ gcnt){
    const int lane = threadIdx.x & 63;
    const int w = threadIdx.x >> 6;
    const int n0 = blockIdx.x * 256;
    const int nend = min(n0 + 256, N);
    float rmax = 0.f, rsum = 0.f;
    int curG = -1, cnt = 0;
    for (int n = n0 + w; n < nend; n += 4){
        int g = batch[n];
        float v = h[(size_t)n * 64 + lane];
        if (g != curG){
            if (curG >= 0){
                atomicMax((int*)&gmx[curG * 64 + lane], __float_as_int(rmax));
                atomicAdd(&gsum[curG * 64 + lane], rsum);
                if (lane == 0) atomicAdd(&gcnt[curG], cnt);
            }
            curG = g; rmax = v; rsum = v; cnt = 1;
        } else {
            rmax = fmaxf(rmax, v); rsum += v; ++cnt;
        }
    }
    if (curG >= 0){
        atomicMax((int*)&gmx[curG * 64 + lane], __float_as_int(rmax));
        atomicAdd(&gsum[curG * 64 + lane], rsum);
        if (lane == 0) atomicAdd(&gcnt[curG], cnt);
    }
}

__global__ void final_linear(const float* __restrict__ gmx, const float* __restrict__ gsum,
                             const int* __restrict__ gcnt,
                             const float* __restrict__ Wout, const float* __restrict__ bout,
                             float* __restrict__ out){
    int t = threadIdx.x;             // one block, 640 threads
    if (t >= 640) return;
    int g = t / 10, oc = t % 10;
    float cnt = (float)max(gcnt[g], 1);
    float acc = bout[oc];
    for (int k = 0; k < 64; ++k)  acc += gmx[g * 64 + k] * Wout[k * 10 + oc];
    for (int k = 0; k < 64; ++k)  acc += (gsum[g * 64 + k] / cnt) * Wout[(64 + k) * 10 + oc];
    out[g * 10 + oc] = acc;
}

// ---------------- launch ----------------
extern "C" void kernel_launch(void* const* d_in, const int* in_sizes, int n_in,
                              void* d_out, int out_size, void* d_ws, size_t ws_size,
                              hipStream_t stream){
    const int N = 50000, E = 800000, B = 64;
    const float* x    = (const float*)d_in[0];
    const int*  ei    = (const int*)d_in[1];
    const int*  batch = (const int*)d_in[2];
    const float *Wl0=(const float*)d_in[3],  *bl0=(const float*)d_in[4],
                *Wr0=(const float*)d_in[5],  *br0=(const float*)d_in[6],
                *att0=(const float*)d_in[7], *bias0=(const float*)d_in[8];
    const float *Wl1=(const float*)d_in[9],  *bl1=(const float*)d_in[10],
                *Wr1=(const float*)d_in[11], *br1=(const float*)d_in[12],
                *att1=(const float*)d_in[13],*bias1=(const float*)d_in[14];
    const float *Wl2=(const float*)d_in[15], *bl2=(const float*)d_in[16],
                *Wr2=(const float*)d_in[17], *br2=(const float*)d_in[18],
                *att2=(const float*)d_in[19],*bias2=(const float*)d_in[20];
    const float *Wout=(const float*)d_in[21],*bout=(const float*)d_in[22];

    const int* srcA = ei;
    const int* dstA = ei + E;

    char* p = (char*)d_ws;
    auto alloc = [&](size_t bytes)->void*{ void* r = (void*)p; p += (bytes + 255) & ~(size_t)255; return r; };
    float* bufA   = (float*)alloc((size_t)N * 192 * 4);
    float* bufB   = (float*)alloc((size_t)N * 192 * 4);
    float* bufC   = (float*)alloc((size_t)N * 192 * 4);
    int* counts   = (int*)alloc((size_t)N * 4);
    int* offsets  = (int*)alloc((size_t)N * 4);
    int* cursor   = (int*)alloc((size_t)N * 4);
    int* blockSums= (int*)alloc(256 * 4);
    int* edge_src = (int*)alloc((size_t)E * 4);
    float* gmx    = (float*)alloc((size_t)B * 64 * 4);
    float* gsum   = (float*)alloc((size_t)B * 64 * 4);
    int* gcnt     = (int*)alloc((size_t)B * 4);

    // CSR build (reused by all 3 layers)
    hipMemsetAsync(counts, 0, (size_t)N * 4, stream);
    int eb = (E + 255) / 256;
    int nb = (N + 255) / 256;
    edge_count<<<eb, 256, 0, stream>>>(srcA, dstA, E, counts);
    scan_block<<<nb, 256, 0, stream>>>(counts, offsets, blockSums, N);
    scan_sums<<<1, 256, 0, stream>>>(blockSums, nb);
    scan_add<<<nb, 256, 0, stream>>>(offsets, blockSums, N);
    copy_int<<<nb, 256, 0, stream>>>(offsets, cursor, N);
    edge_scatter<<<eb, 256, 0, stream>>>(srcA, dstA, E, cursor, edge_src);

    const int rb = (N + 63) / 64;   // 64-row tiles for linears

    // layer 0: 32 -> 192 (H=3, C=64), concat
    dual_linear_t<32, 384, 384><<<rb, 384, 0, stream>>>(x, Wl0, bl0, Wr0, br0, bufB, bufC, N);
    gatv2_agg<3,false><<<(N * 3 + 3) / 4, 256, 0, stream>>>(bufB, bufC, att0, bias0, offsets, counts, edge_src, bufA, N);

    // layer 1: 192 -> 128 (H=2), concat
    dual_linear_t<192, 256, 256><<<rb, 256, 0, stream>>>(bufA, Wl1, bl1, Wr1, br1, bufB, bufC, N);
    gatv2_agg<2,false><<<(N * 2 + 3) / 4, 256, 0, stream>>>(bufB, bufC, att1, bias1, offsets, counts, edge_src, bufA, N);

    // layer 2: 128 -> 128 (H=2), mean over heads -> 64
    dual_linear_t<128, 256, 256><<<rb, 256, 0, stream>>>(bufA, Wl2, bl2, Wr2, br2, bufB, bufC, N);
    gatv2_agg<2,true ><<<(N + 3) / 4, 256, 0, stream>>>(bufB, bufC, att2, bias2, offsets, counts, edge_src, bufA, N);

    // pooling + output linear
    hipMemsetAsync(gmx,  0, (size_t)B * 64 * 4, stream);
    hipMemsetAsync(gsum, 0, (size_t)B * 64 * 4, stream);
    hipMemsetAsync(gcnt, 0, (size_t)B * 4, stream);
    pool_kernel<<<(N + 255) / 256, 256, 0, stream>>>(bufA, batch, N, gmx, gsum, gcnt);
    final_linear<<<1, 640, 0, stream>>>(gmx, gsum, gcnt, Wout, bout, (float*)d_out);
}

// Round 6
// 461.229 us; speedup vs baseline: 1.2437x; 1.2437x over previous
//
#include <hip/hip_runtime.h>
#include <hip/hip_bf16.h>
#include <math.h>

#define NEG_SLOPE 0.2f

typedef __attribute__((ext_vector_type(8))) short short8;
typedef __attribute__((ext_vector_type(4))) float f32x4;

__device__ __forceinline__ unsigned short f2b(float v){   // f32 -> bf16 RNE
    unsigned int b = __float_as_uint(v);
    return (unsigned short)((b + 0x7FFFu + ((b >> 16) & 1u)) >> 16);
}

// ---------------- CSR build ----------------

__global__ void edge_count(const int* __restrict__ src, const int* __restrict__ dst,
                           int E, int* __restrict__ counts){
    int e = blockIdx.x * blockDim.x + threadIdx.x;
    if (e >= E) return;
    int s = src[e], d = dst[e];
    if (s != d) atomicAdd(&counts[d], 1);
}

__global__ void scan_block(const int* __restrict__ counts, int* __restrict__ offsets,
                           int* __restrict__ blockSums, int N){
    __shared__ int sh[256];
    int t = threadIdx.x;
    int i = blockIdx.x * 256 + t;
    int v = (i < N) ? counts[i] : 0;
    sh[t] = v; __syncthreads();
    for (int off = 1; off < 256; off <<= 1){
        int x = (t >= off) ? sh[t - off] : 0;
        __syncthreads();
        sh[t] += x;
        __syncthreads();
    }
    if (i < N) offsets[i] = sh[t] - v;           // exclusive
    if (t == 255) blockSums[blockIdx.x] = sh[255];
}

__global__ void scan_sums(int* __restrict__ blockSums, int nb){
    __shared__ int sh[256];
    int t = threadIdx.x;
    int v = (t < nb) ? blockSums[t] : 0;
    sh[t] = v; __syncthreads();
    for (int off = 1; off < 256; off <<= 1){
        int x = (t >= off) ? sh[t - off] : 0;
        __syncthreads();
        sh[t] += x;
        __syncthreads();
    }
    if (t < nb) blockSums[t] = sh[t] - v;        // exclusive
}

__global__ void scan_add(int* __restrict__ offsets, const int* __restrict__ blockSums, int N){
    int i = blockIdx.x * 256 + threadIdx.x;
    if (i < N) offsets[i] += blockSums[blockIdx.x];
}

__global__ void copy_int(const int* __restrict__ a, int* __restrict__ b, int N){
    int i = blockIdx.x * blockDim.x + threadIdx.x;
    if (i < N) b[i] = a[i];
}

__global__ void edge_scatter(const int* __restrict__ src, const int* __restrict__ dst,
                             int E, int* __restrict__ cursor, int* __restrict__ edge_src){
    int e = blockIdx.x * blockDim.x + threadIdx.x;
    if (e >= E) return;
    int s = src[e], d = dst[e];
    if (s != d){
        int pos = atomicAdd(&cursor[d], 1);
        edge_src[pos] = s;
    }
}

// ---------------- WT build: [Wl|Wr] (K x HC each, f32) -> WT bf16 [2HC][K] ----------------
__global__ void build_wt(const float* __restrict__ Wl, const float* __restrict__ Wr,
                         int K, int HC, unsigned short* __restrict__ WT, int total){
    int i = blockIdx.x * 256 + threadIdx.x;
    if (i >= total) return;
    int c = i / K, k = i - c * K;
    float v = (c < HC) ? Wl[(size_t)k * HC + c] : Wr[(size_t)k * HC + (c - HC)];
    WT[i] = f2b(v);
}

// ---------------- MFMA dual linear ----------------
// [xl | xr] = in @ [Wl | Wr] + [bl | br], xl emitted as bf16 (gather table),
// xr as f32. Block: 64 rows x COLS cols, 4 waves; wave w owns cols
// [w*CT*16, (w+1)*CT*16), 4 row-tiles of 16. mfma_f32_16x16x32_bf16:
// A row=lane&15, k=(lane>>4)*8+j ; B col=lane&15, same k ; C/D col=lane&15,
// row=(lane>>4)*4+reg  [m89/m91 verified].
template<int K, int COLS, int HC>
__global__ __launch_bounds__(256)
void mfma_dual_linear(const float* __restrict__ in,          // N x K (f32)
                      const unsigned short* __restrict__ WT, // COLS x K (bf16)
                      const float* __restrict__ bl, const float* __restrict__ br,
                      unsigned short* __restrict__ xlb,      // N x HC (bf16)
                      float* __restrict__ xr,                // N x HC (f32)
                      int N){
    constexpr int KP = K + 8;              // row pad: keeps 16B alignment, breaks bank stride
    constexpr int CT = COLS / 64;          // col-tiles per wave
    __shared__ __align__(16) unsigned short xs[64 * KP];
    const int tid = threadIdx.x;
    const int row0 = blockIdx.x * 64;

    // stage 64 rows, f32 -> bf16
    {
        const int r = tid >> 2, q = tid & 3;
        int gr = row0 + r; if (gr > N - 1) gr = N - 1;
        const float* ip = in + (size_t)gr * K + q * (K / 4);
        unsigned short* op = &xs[r * KP + q * (K / 4)];
        #pragma unroll
        for (int kk = 0; kk < K / 4; kk += 4){
            float4 v = *(const float4*)&ip[kk];
            ushort4 o;
            o.x = f2b(v.x); o.y = f2b(v.y); o.z = f2b(v.z); o.w = f2b(v.w);
            *(ushort4*)&op[kk] = o;
        }
    }
    __syncthreads();

    const int w = tid >> 6, lane = tid & 63;
    const int lr = lane & 15, lk = (lane >> 4) * 8;

    f32x4 acc[CT][4];
    #pragma unroll
    for (int ct = 0; ct < CT; ++ct){
        int c = (w * CT + ct) * 16 + lr;
        float bv = (c < HC) ? bl[c] : br[c - HC];
        #pragma unroll
        for (int rt = 0; rt < 4; ++rt) acc[ct][rt] = {bv, bv, bv, bv};
    }

    #pragma unroll
    for (int ks = 0; ks < K / 32; ++ks){
        short8 a[4];
        #pragma unroll
        for (int rt = 0; rt < 4; ++rt)
            a[rt] = *(const short8*)&xs[(rt * 16 + lr) * KP + ks * 32 + lk];
        #pragma unroll
        for (int ct = 0; ct < CT; ++ct){
            int c = (w * CT + ct) * 16 + lr;
            short8 b = *(const short8*)&WT[(size_t)c * K + ks * 32 + lk];
            #pragma unroll
            for (int rt = 0; rt < 4; ++rt)
                acc[ct][rt] = __builtin_amdgcn_mfma_f32_16x16x32_bf16(a[rt], b, acc[ct][rt], 0, 0, 0);
        }
    }

    #pragma unroll
    for (int ct = 0; ct < CT; ++ct){
        int c = (w * CT + ct) * 16 + lr;
        #pragma unroll
        for (int rt = 0; rt < 4; ++rt){
            #pragma unroll
            for (int r = 0; r < 4; ++r){
                int row = row0 + rt * 16 + (lane >> 4) * 4 + r;
                if (row < N){
                    float v = acc[ct][rt][r];
                    if (c < HC) xlb[(size_t)row * HC + c] = f2b(v);
                    else        xr [(size_t)row * HC + (c - HC)] = v;
                }
            }
        }
    }
}

// ---------------- GATv2 aggregation (bf16 gather table) ----------------
// One wave per (node [, head]); 4 groups x 16 lanes; online softmax with
// defer-max (THR=8) + 2-deep prefetch. xl gathered as 4x bf16 (8 B/lane).
template<int H, bool MEAN>
__global__ __launch_bounds__(256)
void gatv2_agg(const unsigned short* __restrict__ xlb, const float* __restrict__ xr,
               const float* __restrict__ att, const float* __restrict__ bias,
               const int* __restrict__ offsets, const int* __restrict__ counts,
               const int* __restrict__ edge_src,
               float* __restrict__ hout, int N){
    const int HC = H * 64;
    int wid  = (blockIdx.x * 256 + threadIdx.x) >> 6;
    int lane = threadIdx.x & 63;
    int g = lane >> 4, sl = lane & 15, cb = sl * 4;
    int n, h0, h1;
    if (MEAN){ n = wid; h0 = 0; h1 = H; }
    else     { n = wid / H; h0 = wid - n * H; h1 = h0 + 1; }
    if (n >= N) return;
    const int rs = offsets[n];
    const int total = counts[n] + 1;     // + implicit self loop (virtual idx 0)

    float ox = 0.f, oy = 0.f, oz = 0.f, ow = 0.f;
    for (int h = h0; h < h1; ++h){
        const float4 a4 = *(const float4*)&att[h * 64 + cb];
        const float4 q4 = *(const float4*)&xr[(size_t)n * HC + h * 64 + cb];
        const unsigned short* XT = xlb + h * 64 + cb;
        float m = -INFINITY, den = 0.f;
        float ax = 0.f, ay = 0.f, az = 0.f, aw = 0.f;
        int j = g;
        if (j < total){
            int scur = (j == 0) ? n : edge_src[rs + j - 1];
            uint2 u = *(const uint2*)&XT[(size_t)scur * HC];
            while (j < total){
                int jn = j + 4;
                int sn = (jn < total) ? edge_src[rs + jn - 1] : scur;
                uint2 un = *(const uint2*)&XT[(size_t)sn * HC];   // prefetch
                float x0 = __uint_as_float(u.x << 16);
                float x1 = __uint_as_float(u.x & 0xFFFF0000u);
                float x2 = __uint_as_float(u.y << 16);
                float x3 = __uint_as_float(u.y & 0xFFFF0000u);
                float t0 = q4.x + x0, t1 = q4.y + x1;
                float t2 = q4.z + x2, t3 = q4.w + x3;
                t0 = t0 > 0.f ? t0 : NEG_SLOPE * t0;
                t1 = t1 > 0.f ? t1 : NEG_SLOPE * t1;
                t2 = t2 > 0.f ? t2 : NEG_SLOPE * t2;
                t3 = t3 > 0.f ? t3 : NEG_SLOPE * t3;
                float p = a4.x * t0 + a4.y * t1 + a4.z * t2 + a4.w * t3;
                p += __shfl_xor(p, 1, 64);
                p += __shfl_xor(p, 2, 64);
                p += __shfl_xor(p, 4, 64);
                p += __shfl_xor(p, 8, 64);
                float d = p - m;                 // first iter: +inf
                if (d > 8.f){                    // rare record jump -> rescale
                    float s = __expf(-d);        // first iter: exp(-inf)=0
                    den *= s; ax *= s; ay *= s; az *= s; aw *= s;
                    m = p; d = 0.f;
                }
                float eb = __expf(d);            // <= e^8, bounded
                den += eb;
                ax += eb * x0; ay += eb * x1;
                az += eb * x2; aw += eb * x3;
                u = un; j = jn;
            }
        }
        // merge the 4 group states (exact for any per-group reference m)
        #pragma unroll
        for (int off = 16; off <= 32; off <<= 1){
            float mo  = __shfl_xor(m,  off, 64);
            float dno = __shfl_xor(den, off, 64);
            float bx = __shfl_xor(ax, off, 64), by = __shfl_xor(ay, off, 64);
            float bz = __shfl_xor(az, off, 64), bw = __shfl_xor(aw, off, 64);
            float Mn = fmaxf(m, mo);
            float sa = (m  == -INFINITY) ? 0.f : __expf(m  - Mn);
            float sb = (mo == -INFINITY) ? 0.f : __expf(mo - Mn);
            den = den * sa + dno * sb;
            ax = ax * sa + bx * sb; ay = ay * sa + by * sb;
            az = az * sa + bz * sb; aw = aw * sa + bw * sb;
            m = Mn;
        }
        float inv = 1.f / den;                   // self loop: den > 0
        ox += ax * inv; oy += ay * inv; oz += az * inv; ow += aw * inv;
    }
    if (lane < 16){
        float4 o;
        if (MEAN){
            const float s = 1.f / H;
            const float4 bv = *(const float4*)&bias[cb];
            o.x = fmaxf(ox * s + bv.x, 0.f);
            o.y = fmaxf(oy * s + bv.y, 0.f);
            o.z = fmaxf(oz * s + bv.z, 0.f);
            o.w = fmaxf(ow * s + bv.w, 0.f);
            *(float4*)&hout[(size_t)n * 64 + cb] = o;
        } else {
            const float4 bv = *(const float4*)&bias[h0 * 64 + cb];
            o.x = fmaxf(ox + bv.x, 0.f);
            o.y = fmaxf(oy + bv.y, 0.f);
            o.z = fmaxf(oz + bv.z, 0.f);
            o.w = fmaxf(ow + bv.w, 0.f);
            *(float4*)&hout[(size_t)n * HC + h0 * 64 + cb] = o;
        }
    }
}

// ---------------- pooling (run-length local reduce; batch is sorted) ----------------
__global__ __launch_bounds__(256)
void pool_kernel(const float* __restrict__ h, const int* __restrict__ batch,
                 int N, float* __restrict__ gmx, float* __restrict__ gsum,
                 int* __restrict__ gcnt){
    const int lane = threadIdx.x & 63;
    const int w = threadIdx.x >> 6;
    const int n0 = blockIdx.x * 256;
    const int nend = min(n0 + 256, N);
    float rmax = 0.f, rsum = 0.f;
    int curG = -1, cnt = 0;
    for (int n = n0 + w; n < nend; n += 4){
        int g = batch[n];
        float v = h[(size_t)n * 64 + lane];
        if (g != curG){
            if (curG >= 0){
                atomicMax((int*)&gmx[curG * 64 + lane], __float_as_int(rmax));
                atomicAdd(&gsum[curG * 64 + lane], rsum);
                if (lane == 0) atomicAdd(&gcnt[curG], cnt);
            }
            curG = g; rmax = v; rsum = v; cnt = 1;
        } else {
            rmax = fmaxf(rmax, v); rsum += v; ++cnt;
        }
    }
    if (curG >= 0){
        atomicMax((int*)&gmx[curG * 64 + lane], __float_as_int(rmax));
        atomicAdd(&gsum[curG * 64 + lane], rsum);
        if (lane == 0) atomicAdd(&gcnt[curG], cnt);
    }
}

__global__ void final_linear(const float* __restrict__ gmx, const float* __restrict__ gsum,
                             const int* __restrict__ gcnt,
                             const float* __restrict__ Wout, const float* __restrict__ bout,
                             float* __restrict__ out){
    int t = threadIdx.x;             // one block, 640 threads
    if (t >= 640) return;
    int g = t / 10, oc = t % 10;
    float cnt = (float)max(gcnt[g], 1);
    float acc = bout[oc];
    for (int k = 0; k < 64; ++k)  acc += gmx[g * 64 + k] * Wout[k * 10 + oc];
    for (int k = 0; k < 64; ++k)  acc += (gsum[g * 64 + k] / cnt) * Wout[(64 + k) * 10 + oc];
    out[g * 10 + oc] = acc;
}

// ---------------- launch ----------------
extern "C" void kernel_launch(void* const* d_in, const int* in_sizes, int n_in,
                              void* d_out, int out_size, void* d_ws, size_t ws_size,
                              hipStream_t stream){
    const int N = 50000, E = 800000, B = 64;
    const float* x    = (const float*)d_in[0];
    const int*  ei    = (const int*)d_in[1];
    const int*  batch = (const int*)d_in[2];
    const float *Wl0=(const float*)d_in[3],  *bl0=(const float*)d_in[4],
                *Wr0=(const float*)d_in[5],  *br0=(const float*)d_in[6],
                *att0=(const float*)d_in[7], *bias0=(const float*)d_in[8];
    const float *Wl1=(const float*)d_in[9],  *bl1=(const float*)d_in[10],
                *Wr1=(const float*)d_in[11], *br1=(const float*)d_in[12],
                *att1=(const float*)d_in[13],*bias1=(const float*)d_in[14];
    const float *Wl2=(const float*)d_in[15], *bl2=(const float*)d_in[16],
                *Wr2=(const float*)d_in[17], *br2=(const float*)d_in[18],
                *att2=(const float*)d_in[19],*bias2=(const float*)d_in[20];
    const float *Wout=(const float*)d_in[21],*bout=(const float*)d_in[22];

    const int* srcA = ei;
    const int* dstA = ei + E;

    char* p = (char*)d_ws;
    auto alloc = [&](size_t bytes)->void*{ void* r = (void*)p; p += (bytes + 255) & ~(size_t)255; return r; };
    float* bufA   = (float*)alloc((size_t)N * 192 * 4);           // h (f32)
    float* bufC   = (float*)alloc((size_t)N * 192 * 4);           // xr (f32)
    unsigned short* xlb = (unsigned short*)alloc((size_t)N * 192 * 2); // xl (bf16)
    unsigned short* WT0 = (unsigned short*)alloc((size_t)384 * 32 * 2);
    unsigned short* WT1 = (unsigned short*)alloc((size_t)256 * 192 * 2);
    unsigned short* WT2 = (unsigned short*)alloc((size_t)256 * 128 * 2);
    int* counts   = (int*)alloc((size_t)N * 4);
    int* offsets  = (int*)alloc((size_t)N * 4);
    int* cursor   = (int*)alloc((size_t)N * 4);
    int* blockSums= (int*)alloc(256 * 4);
    int* edge_src = (int*)alloc((size_t)E * 4);
    float* gmx    = (float*)alloc((size_t)B * 64 * 4);
    float* gsum   = (float*)alloc((size_t)B * 64 * 4);
    int* gcnt     = (int*)alloc((size_t)B * 4);

    // weight transpose+bf16 (tiny)
    build_wt<<<(384 * 32 + 255) / 256, 256, 0, stream>>>(Wl0, Wr0, 32, 192, WT0, 384 * 32);
    build_wt<<<(256 * 192 + 255) / 256, 256, 0, stream>>>(Wl1, Wr1, 192, 128, WT1, 256 * 192);
    build_wt<<<(256 * 128 + 255) / 256, 256, 0, stream>>>(Wl2, Wr2, 128, 128, WT2, 256 * 128);

    // CSR build (reused by all 3 layers)
    hipMemsetAsync(counts, 0, (size_t)N * 4, stream);
    int eb = (E + 255) / 256;
    int nb = (N + 255) / 256;
    edge_count<<<eb, 256, 0, stream>>>(srcA, dstA, E, counts);
    scan_block<<<nb, 256, 0, stream>>>(counts, offsets, blockSums, N);
    scan_sums<<<1, 256, 0, stream>>>(blockSums, nb);
    scan_add<<<nb, 256, 0, stream>>>(offsets, blockSums, N);
    copy_int<<<nb, 256, 0, stream>>>(offsets, cursor, N);
    edge_scatter<<<eb, 256, 0, stream>>>(srcA, dstA, E, cursor, edge_src);

    const int rb = (N + 63) / 64;   // 64-row tiles

    // layer 0: 32 -> 192 (H=3, C=64), concat
    mfma_dual_linear<32, 384, 192><<<rb, 256, 0, stream>>>(x, WT0, bl0, br0, xlb, bufC, N);
    gatv2_agg<3,false><<<(N * 3 + 3) / 4, 256, 0, stream>>>(xlb, bufC, att0, bias0, offsets, counts, edge_src, bufA, N);

    // layer 1: 192 -> 128 (H=2), concat
    mfma_dual_linear<192, 256, 128><<<rb, 256, 0, stream>>>(bufA, WT1, bl1, br1, xlb, bufC, N);
    gatv2_agg<2,false><<<(N * 2 + 3) / 4, 256, 0, stream>>>(xlb, bufC, att1, bias1, offsets, counts, edge_src, bufA, N);

    // layer 2: 128 -> 128 (H=2), mean over heads -> 64
    mfma_dual_linear<128, 256, 128><<<rb, 256, 0, stream>>>(bufA, WT2, bl2, br2, xlb, bufC, N);
    gatv2_agg<2,true ><<<(N + 3) / 4, 256, 0, stream>>>(xlb, bufC, att2, bias2, offsets, counts, edge_src, bufA, N);

    // pooling + output linear
    hipMemsetAsync(gmx,  0, (size_t)B * 64 * 4, stream);
    hipMemsetAsync(gsum, 0, (size_t)B * 64 * 4, stream);
    hipMemsetAsync(gcnt, 0, (size_t)B * 4, stream);
    pool_kernel<<<(N + 255) / 256, 256, 0, stream>>>(bufA, batch, N, gmx, gsum, gcnt);
    final_linear<<<1, 640, 0, stream>>>(gmx, gsum, gcnt, Wout, bout, (float*)d_out);
}

// Round 7
// 409.743 us; speedup vs baseline: 1.4000x; 1.1257x over previous
//
#include <hip/hip_runtime.h>
#include <hip/hip_bf16.h>
#include <math.h>

#define NEG_SLOPE 0.2f

typedef __attribute__((ext_vector_type(8))) short short8;
typedef __attribute__((ext_vector_type(4))) float f32x4;

__device__ __forceinline__ unsigned short f2b(float v){   // f32 -> bf16 RNE
    unsigned int b = __float_as_uint(v);
    return (unsigned short)((b + 0x7FFFu + ((b >> 16) & 1u)) >> 16);
}

// sum across 16-lane group via ds_swizzle (imm pattern, no addr VGPRs)
__device__ __forceinline__ float swz_add16(float p){
    int q;
    q = __builtin_amdgcn_ds_swizzle(__float_as_int(p), 0x041F); p += __int_as_float(q); // xor 1
    q = __builtin_amdgcn_ds_swizzle(__float_as_int(p), 0x081F); p += __int_as_float(q); // xor 2
    q = __builtin_amdgcn_ds_swizzle(__float_as_int(p), 0x101F); p += __int_as_float(q); // xor 4
    q = __builtin_amdgcn_ds_swizzle(__float_as_int(p), 0x201F); p += __int_as_float(q); // xor 8
    return p;
}

// ---------------- CSR build ----------------

__global__ void edge_count(const int* __restrict__ src, const int* __restrict__ dst,
                           int E, int* __restrict__ counts){
    int e = blockIdx.x * blockDim.x + threadIdx.x;
    if (e >= E) return;
    int s = src[e], d = dst[e];
    if (s != d) atomicAdd(&counts[d], 1);
}

__global__ void scan_block(const int* __restrict__ counts, int* __restrict__ offsets,
                           int* __restrict__ blockSums, int N){
    __shared__ int sh[256];
    int t = threadIdx.x;
    int i = blockIdx.x * 256 + t;
    int v = (i < N) ? counts[i] : 0;
    sh[t] = v; __syncthreads();
    for (int off = 1; off < 256; off <<= 1){
        int x = (t >= off) ? sh[t - off] : 0;
        __syncthreads();
        sh[t] += x;
        __syncthreads();
    }
    if (i < N) offsets[i] = sh[t] - v;           // exclusive
    if (t == 255) blockSums[blockIdx.x] = sh[255];
}

__global__ void scan_sums(int* __restrict__ blockSums, int nb){
    __shared__ int sh[256];
    int t = threadIdx.x;
    int v = (t < nb) ? blockSums[t] : 0;
    sh[t] = v; __syncthreads();
    for (int off = 1; off < 256; off <<= 1){
        int x = (t >= off) ? sh[t - off] : 0;
        __syncthreads();
        sh[t] += x;
        __syncthreads();
    }
    if (t < nb) blockSums[t] = sh[t] - v;        // exclusive
}

__global__ void scan_add(int* __restrict__ offsets, const int* __restrict__ blockSums, int N){
    int i = blockIdx.x * 256 + threadIdx.x;
    if (i < N) offsets[i] += blockSums[blockIdx.x];
}

__global__ void copy_int(const int* __restrict__ a, int* __restrict__ b, int N){
    int i = blockIdx.x * blockDim.x + threadIdx.x;
    if (i < N) b[i] = a[i];
}

__global__ void edge_scatter(const int* __restrict__ src, const int* __restrict__ dst,
                             int E, int* __restrict__ cursor, int* __restrict__ edge_src){
    int e = blockIdx.x * blockDim.x + threadIdx.x;
    if (e >= E) return;
    int s = src[e], d = dst[e];
    if (s != d){
        int pos = atomicAdd(&cursor[d], 1);
        edge_src[pos] = s;
    }
}

// edge node ids -> row byte offsets for the two table geometries
__global__ void scale_edges(const int* __restrict__ es, int m,
                            int* __restrict__ e384, int* __restrict__ e256){
    int i = blockIdx.x * 256 + threadIdx.x;
    if (i >= m) return;
    int s = es[i];
    e384[i] = s * 384;   // HC=192, bf16
    e256[i] = s * 256;   // HC=128, bf16
}

// ---------------- WT build: [Wl|Wr] (K x HC each, f32) -> WT bf16 [2HC][K] ----------------
__global__ void build_wt(const float* __restrict__ Wl, const float* __restrict__ Wr,
                         int K, int HC, unsigned short* __restrict__ WT, int total){
    int i = blockIdx.x * 256 + threadIdx.x;
    if (i >= total) return;
    int c = i / K, k = i - c * K;
    float v = (c < HC) ? Wl[(size_t)k * HC + c] : Wr[(size_t)k * HC + (c - HC)];
    WT[i] = f2b(v);
}

// ---------------- MFMA dual linear ----------------
// [xl | xr] = in @ [Wl | Wr] + [bl | br]; xl emitted bf16, xr f32.
// Input f32 (INB=false) or bf16 (INB=true). Block: 64 rows, 4 waves.
template<int K, int COLS, int HC, bool INB>
__global__ __launch_bounds__(256)
void mfma_dual_linear(const void* __restrict__ in_,
                      const unsigned short* __restrict__ WT, // COLS x K (bf16)
                      const float* __restrict__ bl, const float* __restrict__ br,
                      unsigned short* __restrict__ xlb,      // N x HC (bf16)
                      float* __restrict__ xr,                // N x HC (f32)
                      int N){
    constexpr int KP = K + 8;
    constexpr int CT = COLS / 64;
    __shared__ __align__(16) unsigned short xs[64 * KP];
    const int tid = threadIdx.x;
    const int row0 = blockIdx.x * 64;

    // stage 64 rows into LDS as bf16
    {
        const int r = tid >> 2, q = tid & 3;
        int gr = row0 + r; if (gr > N - 1) gr = N - 1;
        unsigned short* op = &xs[r * KP + q * (K / 4)];
        if (INB){
            const unsigned short* ip = (const unsigned short*)in_ + (size_t)gr * K + q * (K / 4);
            #pragma unroll
            for (int kk = 0; kk < K / 4; kk += 8)
                *(uint4*)&op[kk] = *(const uint4*)&ip[kk];
        } else {
            const float* ip = (const float*)in_ + (size_t)gr * K + q * (K / 4);
            #pragma unroll
            for (int kk = 0; kk < K / 4; kk += 4){
                float4 v = *(const float4*)&ip[kk];
                ushort4 o;
                o.x = f2b(v.x); o.y = f2b(v.y); o.z = f2b(v.z); o.w = f2b(v.w);
                *(ushort4*)&op[kk] = o;
            }
        }
    }
    __syncthreads();

    const int w = tid >> 6, lane = tid & 63;
    const int lr = lane & 15, lk = (lane >> 4) * 8;

    f32x4 acc[CT][4];
    #pragma unroll
    for (int ct = 0; ct < CT; ++ct){
        int c = (w * CT + ct) * 16 + lr;
        float bv = (c < HC) ? bl[c] : br[c - HC];
        #pragma unroll
        for (int rt = 0; rt < 4; ++rt) acc[ct][rt] = {bv, bv, bv, bv};
    }

    #pragma unroll
    for (int ks = 0; ks < K / 32; ++ks){
        short8 a[4];
        #pragma unroll
        for (int rt = 0; rt < 4; ++rt)
            a[rt] = *(const short8*)&xs[(rt * 16 + lr) * KP + ks * 32 + lk];
        #pragma unroll
        for (int ct = 0; ct < CT; ++ct){
            int c = (w * CT + ct) * 16 + lr;
            short8 b = *(const short8*)&WT[(size_t)c * K + ks * 32 + lk];
            #pragma unroll
            for (int rt = 0; rt < 4; ++rt)
                acc[ct][rt] = __builtin_amdgcn_mfma_f32_16x16x32_bf16(a[rt], b, acc[ct][rt], 0, 0, 0);
        }
    }

    #pragma unroll
    for (int ct = 0; ct < CT; ++ct){
        int c = (w * CT + ct) * 16 + lr;
        #pragma unroll
        for (int rt = 0; rt < 4; ++rt){
            #pragma unroll
            for (int r = 0; r < 4; ++r){
                int row = row0 + rt * 16 + (lane >> 4) * 4 + r;
                if (row < N){
                    float v = acc[ct][rt][r];
                    if (c < HC) xlb[(size_t)row * HC + c] = f2b(v);
                    else        xr [(size_t)row * HC + (c - HC)] = v;
                }
            }
        }
    }
}

// ---------------- GATv2 aggregation ----------------
// One wave per (node [, head]); 4 groups x 16 lanes; online softmax with
// defer-max (THR=8), 32-bit saddr gathers via pre-scaled byte offsets,
// ds_swizzle reduction, 2-deep index / 1-deep row prefetch.
template<int H, bool MEAN, bool OUTB>
__global__ __launch_bounds__(256)
void gatv2_agg(const unsigned short* __restrict__ xlb, const float* __restrict__ xr,
               const float* __restrict__ att, const float* __restrict__ bias,
               const int* __restrict__ offsets, const int* __restrict__ counts,
               const int* __restrict__ ebyte,   // row byte offsets, padded +8
               void* __restrict__ hout, int N){
    const int HC = H * 64;
    const int RB = HC * 2;                 // xlb row bytes
    int wid  = (blockIdx.x * 256 + threadIdx.x) >> 6;
    int lane = threadIdx.x & 63;
    int g = lane >> 4, sl = lane & 15, cb = sl * 4;
    int n, h0, h1;
    if (MEAN){ n = wid; h0 = 0; h1 = H; }
    else     { n = wid / H; h0 = wid - n * H; h1 = h0 + 1; }
    if (n >= N) return;
    const int rs = offsets[n];
    const int total = counts[n] + 1;       // + implicit self loop (virtual idx 0)
    const char* XB = (const char*)xlb;
    const unsigned selfb = (unsigned)(n * RB);

    float ox = 0.f, oy = 0.f, oz = 0.f, ow = 0.f;
    for (int h = h0; h < h1; ++h){
        const float4 a4 = *(const float4*)&att[h * 64 + cb];
        const float4 q4 = *(const float4*)&xr[(size_t)n * HC + h * 64 + cb];
        const unsigned colb = (unsigned)((h * 64 + cb) * 2);
        float m = -INFINITY, den = 0.f;
        float ax = 0.f, ay = 0.f, az = 0.f, aw = 0.f;
        int vi = g;
        if (vi < total){
            unsigned boff = (g == 0) ? selfb : (unsigned)ebyte[rs + g - 1];
            uint2 u = *(const uint2*)(XB + (boff + colb));
            unsigned boffn = (unsigned)ebyte[rs + vi + 3];       // vi+4 (padded-safe)
            while (vi < total){
                int vin = vi + 4;
                uint2 un = *(const uint2*)(XB + (boffn + colb)); // row prefetch
                boffn = (unsigned)ebyte[rs + vin + 3];           // vi+8 (padded-safe)
                float x0 = __uint_as_float(u.x << 16);
                float x1 = __uint_as_float(u.x & 0xFFFF0000u);
                float x2 = __uint_as_float(u.y << 16);
                float x3 = __uint_as_float(u.y & 0xFFFF0000u);
                float t0 = q4.x + x0, t1 = q4.y + x1;
                float t2 = q4.z + x2, t3 = q4.w + x3;
                t0 = fmaxf(t0, NEG_SLOPE * t0);
                t1 = fmaxf(t1, NEG_SLOPE * t1);
                t2 = fmaxf(t2, NEG_SLOPE * t2);
                t3 = fmaxf(t3, NEG_SLOPE * t3);
                float p = a4.x * t0 + a4.y * t1 + a4.z * t2 + a4.w * t3;
                p = swz_add16(p);
                float d = p - m;                 // first iter: +inf
                if (d > 8.f){                    // rare record jump -> rescale
                    float s = __expf(-d);        // first iter: exp(-inf)=0
                    den *= s; ax *= s; ay *= s; az *= s; aw *= s;
                    m = p; d = 0.f;
                }
                float eb = __expf(d);            // <= e^8, bounded
                den += eb;
                ax += eb * x0; ay += eb * x1;
                az += eb * x2; aw += eb * x3;
                u = un; vi = vin;
            }
        }
        // merge the 4 group states (exact for any per-group reference m)
        #pragma unroll
        for (int off = 16; off <= 32; off <<= 1){
            float mo  = __shfl_xor(m,  off, 64);
            float dno = __shfl_xor(den, off, 64);
            float bx = __shfl_xor(ax, off, 64), by = __shfl_xor(ay, off, 64);
            float bz = __shfl_xor(az, off, 64), bw = __shfl_xor(aw, off, 64);
            float Mn = fmaxf(m, mo);
            float sa = (m  == -INFINITY) ? 0.f : __expf(m  - Mn);
            float sb = (mo == -INFINITY) ? 0.f : __expf(mo - Mn);
            den = den * sa + dno * sb;
            ax = ax * sa + bx * sb; ay = ay * sa + by * sb;
            az = az * sa + bz * sb; aw = aw * sa + bw * sb;
            m = Mn;
        }
        float inv = 1.f / den;                   // self loop: den > 0
        ox += ax * inv; oy += ay * inv; oz += az * inv; ow += aw * inv;
    }
    if (lane < 16){
        if (MEAN){
            const float s = 1.f / H;
            const float4 bv = *(const float4*)&bias[cb];
            float4 o;
            o.x = fmaxf(ox * s + bv.x, 0.f);
            o.y = fmaxf(oy * s + bv.y, 0.f);
            o.z = fmaxf(oz * s + bv.z, 0.f);
            o.w = fmaxf(ow * s + bv.w, 0.f);
            *(float4*)&((float*)hout)[(size_t)n * 64 + cb] = o;
        } else {
            const float4 bv = *(const float4*)&bias[h0 * 64 + cb];
            float o0 = fmaxf(ox + bv.x, 0.f), o1 = fmaxf(oy + bv.y, 0.f);
            float o2 = fmaxf(oz + bv.z, 0.f), o3 = fmaxf(ow + bv.w, 0.f);
            if (OUTB){
                uint2 w2;
                w2.x = (unsigned)f2b(o0) | ((unsigned)f2b(o1) << 16);
                w2.y = (unsigned)f2b(o2) | ((unsigned)f2b(o3) << 16);
                *(uint2*)&((unsigned short*)hout)[(size_t)n * HC + h0 * 64 + cb] = w2;
            } else {
                float4 o; o.x = o0; o.y = o1; o.z = o2; o.w = o3;
                *(float4*)&((float*)hout)[(size_t)n * HC + h0 * 64 + cb] = o;
            }
        }
    }
}

// ---------------- pooling (run-length local reduce; batch is sorted) ----------------
__global__ __launch_bounds__(256)
void pool_kernel(const float* __restrict__ h, const int* __restrict__ batch,
                 int N, float* __restrict__ gmx, float* __restrict__ gsum,
                 int* __restrict__ gcnt){
    const int lane = threadIdx.x & 63;
    const int w = threadIdx.x >> 6;
    const int n0 = blockIdx.x * 256;
    const int nend = min(n0 + 256, N);
    float rmax = 0.f, rsum = 0.f;
    int curG = -1, cnt = 0;
    for (int n = n0 + w; n < nend; n += 4){
        int g = batch[n];
        float v = h[(size_t)n * 64 + lane];
        if (g != curG){
            if (curG >= 0){
                atomicMax((int*)&gmx[curG * 64 + lane], __float_as_int(rmax));
                atomicAdd(&gsum[curG * 64 + lane], rsum);
                if (lane == 0) atomicAdd(&gcnt[curG], cnt);
            }
            curG = g; rmax = v; rsum = v; cnt = 1;
        } else {
            rmax = fmaxf(rmax, v); rsum += v; ++cnt;
        }
    }
    if (curG >= 0){
        atomicMax((int*)&gmx[curG * 64 + lane], __float_as_int(rmax));
        atomicAdd(&gsum[curG * 64 + lane], rsum);
        if (lane == 0) atomicAdd(&gcnt[curG], cnt);
    }
}

__global__ void final_linear(const float* __restrict__ gmx, const float* __restrict__ gsum,
                             const int* __restrict__ gcnt,
                             const float* __restrict__ Wout, const float* __restrict__ bout,
                             float* __restrict__ out){
    int t = threadIdx.x;             // one block, 640 threads
    if (t >= 640) return;
    int g = t / 10, oc = t % 10;
    float cnt = (float)max(gcnt[g], 1);
    float acc = bout[oc];
    for (int k = 0; k < 64; ++k)  acc += gmx[g * 64 + k] * Wout[k * 10 + oc];
    for (int k = 0; k < 64; ++k)  acc += (gsum[g * 64 + k] / cnt) * Wout[(64 + k) * 10 + oc];
    out[g * 10 + oc] = acc;
}

// ---------------- launch ----------------
extern "C" void kernel_launch(void* const* d_in, const int* in_sizes, int n_in,
                              void* d_out, int out_size, void* d_ws, size_t ws_size,
                              hipStream_t stream){
    const int N = 50000, E = 800000, B = 64;
    const float* x    = (const float*)d_in[0];
    const int*  ei    = (const int*)d_in[1];
    const int*  batch = (const int*)d_in[2];
    const float *Wl0=(const float*)d_in[3],  *bl0=(const float*)d_in[4],
                *Wr0=(const float*)d_in[5],  *br0=(const float*)d_in[6],
                *att0=(const float*)d_in[7], *bias0=(const float*)d_in[8];
    const float *Wl1=(const float*)d_in[9],  *bl1=(const float*)d_in[10],
                *Wr1=(const float*)d_in[11], *br1=(const float*)d_in[12],
                *att1=(const float*)d_in[13],*bias1=(const float*)d_in[14];
    const float *Wl2=(const float*)d_in[15], *bl2=(const float*)d_in[16],
                *Wr2=(const float*)d_in[17], *br2=(const float*)d_in[18],
                *att2=(const float*)d_in[19],*bias2=(const float*)d_in[20];
    const float *Wout=(const float*)d_in[21],*bout=(const float*)d_in[22];

    const int* srcA = ei;
    const int* dstA = ei + E;

    char* p = (char*)d_ws;
    auto alloc = [&](size_t bytes)->void*{ void* r = (void*)p; p += (bytes + 255) & ~(size_t)255; return r; };
    void*  bufA   = alloc((size_t)N * 192 * 4);                 // h: bf16 (L0,L1) / f32 (L2)
    float* bufC   = (float*)alloc((size_t)N * 192 * 4);         // xr (f32)
    unsigned short* xlb = (unsigned short*)alloc((size_t)N * 192 * 2); // xl (bf16)
    unsigned short* WT0 = (unsigned short*)alloc((size_t)384 * 32 * 2);
    unsigned short* WT1 = (unsigned short*)alloc((size_t)256 * 192 * 2);
    unsigned short* WT2 = (unsigned short*)alloc((size_t)256 * 128 * 2);
    int* counts   = (int*)alloc((size_t)N * 4);
    int* offsets  = (int*)alloc((size_t)N * 4);
    int* cursor   = (int*)alloc((size_t)N * 4);
    int* blockSums= (int*)alloc(256 * 4);
    int* edge_src = (int*)alloc((size_t)(E + 8) * 4);
    int* eb384    = (int*)alloc((size_t)(E + 8) * 4);
    int* eb256    = (int*)alloc((size_t)(E + 8) * 4);
    float* gmx    = (float*)alloc((size_t)B * 64 * 4);
    float* gsum   = (float*)alloc((size_t)B * 64 * 4);
    int* gcnt     = (int*)alloc((size_t)B * 4);

    // weight transpose + bf16 (tiny)
    build_wt<<<(384 * 32 + 255) / 256, 256, 0, stream>>>(Wl0, Wr0, 32, 192, WT0, 384 * 32);
    build_wt<<<(256 * 192 + 255) / 256, 256, 0, stream>>>(Wl1, Wr1, 192, 128, WT1, 256 * 192);
    build_wt<<<(256 * 128 + 255) / 256, 256, 0, stream>>>(Wl2, Wr2, 128, 128, WT2, 256 * 128);

    // CSR build (reused by all 3 layers)
    hipMemsetAsync(counts, 0, (size_t)N * 4, stream);
    hipMemsetAsync(edge_src, 0, (size_t)(E + 8) * 4, stream);
    int eb = (E + 255) / 256;
    int nb = (N + 255) / 256;
    edge_count<<<eb, 256, 0, stream>>>(srcA, dstA, E, counts);
    scan_block<<<nb, 256, 0, stream>>>(counts, offsets, blockSums, N);
    scan_sums<<<1, 256, 0, stream>>>(blockSums, nb);
    scan_add<<<nb, 256, 0, stream>>>(offsets, blockSums, N);
    copy_int<<<nb, 256, 0, stream>>>(offsets, cursor, N);
    edge_scatter<<<eb, 256, 0, stream>>>(srcA, dstA, E, cursor, edge_src);
    scale_edges<<<(E + 8 + 255) / 256, 256, 0, stream>>>(edge_src, E + 8, eb384, eb256);

    const int rb = (N + 63) / 64;   // 64-row tiles

    // layer 0: 32 -> 192 (H=3, C=64), concat; h0 out bf16
    mfma_dual_linear<32, 384, 192, false><<<rb, 256, 0, stream>>>(x, WT0, bl0, br0, xlb, bufC, N);
    gatv2_agg<3, false, true><<<(N * 3 + 3) / 4, 256, 0, stream>>>(xlb, bufC, att0, bias0, offsets, counts, eb384, bufA, N);

    // layer 1: 192 -> 128 (H=2), concat; h1 out bf16
    mfma_dual_linear<192, 256, 128, true><<<rb, 256, 0, stream>>>(bufA, WT1, bl1, br1, xlb, bufC, N);
    gatv2_agg<2, false, true><<<(N * 2 + 3) / 4, 256, 0, stream>>>(xlb, bufC, att1, bias1, offsets, counts, eb256, bufA, N);

    // layer 2: 128 -> 128 (H=2), mean over heads -> 64; out f32 for pooling
    mfma_dual_linear<128, 256, 128, true><<<rb, 256, 0, stream>>>(bufA, WT2, bl2, br2, xlb, bufC, N);
    gatv2_agg<2, true, false><<<(N + 3) / 4, 256, 0, stream>>>(xlb, bufC, att2, bias2, offsets, counts, eb256, bufA, N);

    // pooling + output linear
    hipMemsetAsync(gmx,  0, (size_t)B * 64 * 4, stream);
    hipMemsetAsync(gsum, 0, (size_t)B * 64 * 4, stream);
    hipMemsetAsync(gcnt, 0, (size_t)B * 4, stream);
    pool_kernel<<<(N + 255) / 256, 256, 0, stream>>>((const float*)bufA, batch, N, gmx, gsum, gcnt);
    final_linear<<<1, 640, 0, stream>>>(gmx, gsum, gcnt, Wout, bout, (float*)d_out);
}